// Round 1
// baseline (473.897 us; speedup 1.0000x reference)
//
#include <hip/hip_runtime.h>
#include <cstdint>
#include <cstddef>

constexpr int T_ = 128;
constexpr int S_ = 512;
constexpr int B_ = 256;
constexpr int START_ = T_ - 3;  // 125
constexpr int STOP_  = T_ - 2;  // 126
constexpr float NEGINF_ = -3.402823466e38f;

// ---------------------------------------------------------------------------
// Forward: value-only Viterbi recursion, stores part_hist (S,B,T) fp32.
// One block per batch element b; 256 threads = (j in [0,128)) x (half h).
// Thread (j,h) register-caches trans[h*64 .. h*64+64)[j] (fixed over t).
// part[] broadcast from LDS via float4; two barriers per step.
// Values are bit-exact vs reference: fl is monotone, so
//   max_i fl(fl(part+trans)+e) == fl(max_i fl(part+trans) + e).
// ---------------------------------------------------------------------------
__global__ __launch_bounds__(256) void viterbi_forward(
    const float* __restrict__ feats,   // (B,S,T)
    const float* __restrict__ trans,   // (T,T)
    float* __restrict__ ph)            // (S,B,T) workspace
{
  const int b   = blockIdx.x;
  const int tid = threadIdx.x;
  const int j   = tid & (T_ - 1);
  const int h   = tid >> 7;            // 0 or 1

  __shared__ alignas(16) float part[T_];
  __shared__ float partial[2][T_];

  // trans column j, rows [h*64, h*64+64) -> registers (coalesced across j)
  float tc[64];
  #pragma unroll
  for (int ii = 0; ii < 64; ++ii)
    tc[ii] = trans[(h * 64 + ii) * T_ + j];

  const float* fb = feats + (size_t)b * S_ * T_;

  // t = 0: part0 = emit[0] + trans[START,:]
  float p0 = fb[j] + trans[START_ * T_ + j];
  if (h == 0) {
    part[j] = p0;
    ph[(size_t)b * T_ + j] = p0;       // row (t=0, b)
  }
  float e_next = fb[T_ + j];           // prefetch emit row t=1
  __syncthreads();

  for (int t = 1; t < S_; ++t) {
    float e_cur = e_next;
    if (t + 1 < S_) e_next = fb[(size_t)(t + 1) * T_ + j];

    const float4* p4 = (const float4*)part;
    float ma = NEGINF_, mb = NEGINF_;  // two chains for ILP
    #pragma unroll
    for (int q = 0; q < 16; q += 2) {
      float4 pa = p4[h * 16 + q];
      float a0 = pa.x + tc[4 * q + 0];
      float a1 = pa.y + tc[4 * q + 1];
      float a2 = pa.z + tc[4 * q + 2];
      float a3 = pa.w + tc[4 * q + 3];
      ma = fmaxf(ma, fmaxf(fmaxf(a0, a1), fmaxf(a2, a3)));
      float4 pb = p4[h * 16 + q + 1];
      float b0 = pb.x + tc[4 * q + 4];
      float b1 = pb.y + tc[4 * q + 5];
      float b2 = pb.z + tc[4 * q + 6];
      float b3 = pb.w + tc[4 * q + 7];
      mb = fmaxf(mb, fmaxf(fmaxf(b0, b1), fmaxf(b2, b3)));
    }
    partial[h][j] = fmaxf(ma, mb);
    __syncthreads();
    if (h == 0) {
      float np = fmaxf(partial[0][j], partial[1][j]) + e_cur;
      part[j] = np;
      ph[((size_t)t * B_ + b) * T_ + j] = np;
    }
    __syncthreads();
  }
}

// ---------------------------------------------------------------------------
// Trace: one wave (64 lanes) per batch element.
// bp recomputed only along the decoded path, bit-exact incl. +e and
// first-occurrence argmax semantics: first i with
//   fl(fl(ph_k[i]+trans[i,ptr])+e) == ph_{k+1}[ptr]   (guaranteed nonempty).
// trans transposed into LDS with stride 129 (conflict-free row gather).
// ph/feats rows double-buffered in registers, 8 steps per chunk.
// ---------------------------------------------------------------------------
constexpr int CH_ = 8;

__global__ __launch_bounds__(64) void viterbi_trace(
    const float* __restrict__ feats,   // (B,S,T)
    const void*  __restrict__ mask,    // (B,S) dtype detected at runtime
    const float* __restrict__ trans,   // (T,T)
    const float* __restrict__ ph,      // (S,B,T)
    int* __restrict__ out)             // (B,S) int32
{
  const int b    = blockIdx.x;
  const int lane = threadIdx.x;

  __shared__ float transT[T_ * 129];   // transT[j*129 + i] = trans[i][j]

  #pragma unroll 4
  for (int g = lane; g < T_ * T_; g += 64) {
    int i  = g >> 7;
    int jj = g & (T_ - 1);
    transT[jj * 129 + i] = trans[g];
  }
  __syncthreads();

  // ---- sequence length (mask dtype: int32 / uint8 / float32) ----
  int len = 0;
  {
    const int w0 = *(const int*)mask;   // element[0][0] is always true
    if (w0 == 0x01010101) {
      const unsigned char* m = (const unsigned char*)mask + (size_t)b * S_;
      for (int s = lane; s < S_; s += 64) len += (m[s] != 0);
    } else if (w0 == 0x3F800000) {
      const float* m = (const float*)mask + (size_t)b * S_;
      for (int s = lane; s < S_; s += 64) len += (m[s] != 0.0f);
    } else {
      const int* m = (const int*)mask + (size_t)b * S_;
      for (int s = lane; s < S_; s += 64) len += (m[s] != 0);
    }
    #pragma unroll
    for (int o = 32; o > 0; o >>= 1) len += __shfl_xor(len, o);
  }
  const int lp = len - 1;              // last valid position

  // ---- final pointer: first-occurrence argmax_i(last_part[i]+trans[i,STOP])
  const float* lastrow = ph + ((size_t)lp * B_ + b) * T_;
  float v0 = lastrow[lane]      + transT[STOP_ * 129 + lane];
  float v1 = lastrow[lane + 64] + transT[STOP_ * 129 + 64 + lane];
  float mx = fmaxf(v0, v1);
  #pragma unroll
  for (int o = 32; o > 0; o >>= 1) mx = fmaxf(mx, __shfl_xor(mx, o));
  unsigned long long g0 = __ballot(v0 == mx);
  unsigned long long g1 = __ballot(v1 == mx);
  int pointer = g0 ? (__ffsll(g0) - 1) : (64 + __ffsll(g1) - 1);

  int ptr = pointer;
  if (lane == 0) out[b * S_ + (S_ - 1)] = pointer;

  const float* fb = feats + (size_t)b * S_ * T_;

  float Aph[CH_][2], Apn[CH_][2], Afe[CH_][2];
  float Bph[CH_][2], Bpn[CH_][2], Bfe[CH_][2];

  auto issue = [&](float (&P)[CH_][2], float (&N)[CH_][2], float (&F)[CH_][2],
                   int k0) {
    #pragma unroll
    for (int s = 0; s < CH_; ++s) {
      int k = k0 - s;
      if (k < 0) k = 0;                       // clamped slots are never used
      const float* rp = ph + ((size_t)k       * B_ + b) * T_;
      const float* rn = ph + ((size_t)(k + 1) * B_ + b) * T_;
      const float* rf = fb + (size_t)(k + 1) * T_;
      P[s][0] = rp[lane];      P[s][1] = rp[lane + 64];
      N[s][0] = rn[lane];      N[s][1] = rn[lane + 64];
      F[s][0] = rf[lane];      F[s][1] = rf[lane + 64];
    }
  };

  auto process = [&](float (&P)[CH_][2], float (&N)[CH_][2], float (&F)[CH_][2],
                     int k0) {
    #pragma unroll
    for (int s = 0; s < CH_; ++s) {
      const int kk = k0 - s;
      if (kk >= 0) {
        int val;
        if (kk > lp) {
          val = 0;                            // masked region: bp == 0
        } else if (kk == lp) {
          ptr = pointer;                      // overwritten row
          val = pointer;
        } else {
          float tr0 = transT[ptr * 129 + lane];
          float tr1 = transT[ptr * 129 + 64 + lane];
          const int pl = ptr & 63;
          float e  = __shfl((ptr < 64) ? F[s][0] : F[s][1], pl);
          float tg = __shfl((ptr < 64) ? N[s][0] : N[s][1], pl);
          float c0 = (P[s][0] + tr0) + e;
          float c1 = (P[s][1] + tr1) + e;
          unsigned long long m0 = __ballot(c0 == tg);
          unsigned long long m1 = __ballot(c1 == tg);
          ptr = m0 ? (__ffsll(m0) - 1) : (64 + __ffsll(m1) - 1);
          val = ptr;
        }
        if (lane == 0) out[b * S_ + kk] = val;
      }
    }
  };

  issue(Aph, Apn, Afe, S_ - 2);
  for (int k0 = S_ - 2; k0 >= 0; k0 -= 2 * CH_) {
    issue(Bph, Bpn, Bfe, k0 - CH_);
    process(Aph, Apn, Afe, k0);
    issue(Aph, Apn, Afe, k0 - 2 * CH_);
    process(Bph, Bpn, Bfe, k0 - CH_);
  }
}

extern "C" void kernel_launch(void* const* d_in, const int* in_sizes, int n_in,
                              void* d_out, int out_size, void* d_ws, size_t ws_size,
                              hipStream_t stream) {
  const float* feats = (const float*)d_in[0];   // (B,S,T) fp32
  const void*  mask  = d_in[1];                 // (B,S) bool-ish
  const float* trans = (const float*)d_in[2];   // (T,T) fp32
  float* ph = (float*)d_ws;                     // (S,B,T) fp32 = 64 MB
  int*   out = (int*)d_out;                     // (B,S) int32

  viterbi_forward<<<dim3(B_), dim3(256), 0, stream>>>(feats, trans, ph);
  viterbi_trace  <<<dim3(B_), dim3(64),  0, stream>>>(feats, mask, trans, ph, out);
}